// Round 4
// baseline (451.837 us; speedup 1.0000x reference)
//
#include <hip/hip_runtime.h>
#include <stdint.h>

// Problem constants
#define TS 64
#define BATCH 1024
#define HID 256
#define IMGD 2048

typedef __bf16 bf16_t;
typedef bf16_t bf16x8 __attribute__((ext_vector_type(8)));
typedef float f32x4 __attribute__((ext_vector_type(4)));

// load 8 consecutive fp32 (16B-aligned) and convert to a bf16x8 MFMA fragment
static __device__ __forceinline__ bf16x8 cvt8(const float* __restrict__ p) {
    const f32x4 a = *reinterpret_cast<const f32x4*>(p);
    const f32x4 b = *reinterpret_cast<const f32x4*>(p + 4);
    bf16x8 r;
    r[0] = (bf16_t)a[0]; r[1] = (bf16_t)a[1]; r[2] = (bf16_t)a[2]; r[3] = (bf16_t)a[3];
    r[4] = (bf16_t)b[0]; r[5] = (bf16_t)b[1]; r[6] = (bf16_t)b[2]; r[7] = (bf16_t)b[3];
    return r;
}
// convert two raw f32x4 registers to a bf16x8 fragment (deferred-cvt path)
static __device__ __forceinline__ bf16x8 cvt8r(f32x4 a, f32x4 b) {
    bf16x8 r;
    r[0] = (bf16_t)a[0]; r[1] = (bf16_t)a[1]; r[2] = (bf16_t)a[2]; r[3] = (bf16_t)a[3];
    r[4] = (bf16_t)b[0]; r[5] = (bf16_t)b[1]; r[6] = (bf16_t)b[2]; r[7] = (bf16_t)b[3];
    return r;
}
static __device__ __forceinline__ uint16_t f2bf(float f) {
    union { float f; uint32_t i; } c; c.f = f;
    uint32_t i = c.i;
    i += 0x7fffu + ((i >> 16) & 1u);   // RNE
    return (uint16_t)(i >> 16);
}
static __device__ __forceinline__ float sigm(float x) { return 1.f / (1.f + __expf(-x)); }
static __device__ __forceinline__ float tanh_f(float x) { return 1.f - 2.f / (1.f + __expf(2.f * x)); }

// ---------------------------------------------------------------------------
// Single persistent kernel. 256 blocks x 256 threads. Block (g, ch) owns
// batch rows [16g,16g+16) and hidden units [64ch,64ch+64).
//
// ROUND-7/8 DESIGN (latency-overlap; flag protocol semantics unchanged):
//  1. Loop ordered so both exposed MALL round-trips hide under x-MFMA:
//     spin -> ISSUE peer co-load -> ISSUE raw f32 emb gather -> x-MFMA
//     -> stage peer h into LDS -> barrier -> hh-MFMA (cvt under ds latency).
//  2. Own chunk's h never round-trips through the MALL: each lane ds_writes
//     its own hpack into the (double-buffered, 16KB) LDS tile; the
//     cooperative global load covers only the 3 PEER chunks (768 u64, -25%).
//  3. Embedding prefetch loads raw f32x4 (cvt deferred under Hall ds_read).
//
// ROUND-8 HARDENING: round-3's bench died at container level. Audit found
// one legal-reordering deadlock: producer flag store and consumer spin are
// relaxed atomics on DIFFERENT addresses -- the compiler may sink the flag
// store past the spin loop (all 4 blocks withhold flags while spinning ->
// deadlock). Zero-cost asm compiler fences now pin the flag store before
// loop-back and the spin after it. No runtime-cost change.
//
// Sync per step: h stores -> __syncthreads (vmcnt drained before s_barrier
// -> stores performed at coherence point) -> thread0 relaxed flag store.
// Consumers: threads 0..2 poll one peer flag each, then barrier.
//
// CRITICAL: all register-array indices compile-time constant (round-4
// lesson: runtime indexing demotes to scratch -> 790MB HBM refetch).
// ---------------------------------------------------------------------------
__global__ __launch_bounds__(256, 1) void lstm_kernel(
    const float* __restrict__ img_feature, const int* __restrict__ caption,
    const float* __restrict__ W_img, const float* __restrict__ b_img,
    const float* __restrict__ emb,
    const float* __restrict__ W_ih, const float* __restrict__ W_hh,
    const float* __restrict__ b_ih, const float* __restrict__ b_hh,
    unsigned long long* __restrict__ h_buf64,
    unsigned* __restrict__ ctr, float* __restrict__ out)
{
    const int g = blockIdx.x & 63, ch = blockIdx.x >> 6;
    const int b0 = g * 16, u0 = ch * 64;
    const int w = threadIdx.x >> 6, lane = threadIdx.x & 63;
    const int quad = lane >> 4, j = lane & 15;
    const int uw = u0 + w * 16;          // wave's first unit (16-unit tile)
    const int ulane = uw + quad * 4;     // this lane's first unit (owns 4)
    const int brow = b0 + j;             // this lane's batch row
    unsigned* flags = ctr + g * 16;      // 4 flags in one 64B line per group

    // double-buffered 16-row x 512B h tile, XOR-swizzled:
    // phys(row r, byte b) = r*512 + (b ^ (r<<4))
    __shared__ unsigned long long hlds[2][1024];

    // ---- img prologue first (before persistent regs go live)
    float imgv[4];
    {
        f32x4 D = {};
        const float* aw = W_img + (size_t)(uw + j) * IMGD + quad * 8;
        const float* bx = img_feature + (size_t)brow * IMGD + quad * 8;
        for (int kk = 0; kk < 64; ++kk) {
            bf16x8 a = cvt8(aw + kk * 32);
            bf16x8 b = cvt8(bx + kk * 32);
            D = __builtin_amdgcn_mfma_f32_16x16x32_bf16(a, b, D, 0, 0, 0);
        }
#pragma unroll
        for (int r = 0; r < 4; ++r) {
            float v = D[r] + b_img[ulane + r];
            imgv[r] = v > 0.f ? v : 0.f;
        }
    }

    // ---- persistent weight A-fragments (live in AGPRs; static indices!)
    bf16x8 Aih[4][8], Ahh[4][8];
#pragma unroll
    for (int q = 0; q < 4; ++q) {
        const int r = q * HID + uw + j;
        const float* pih = W_ih + (size_t)r * HID + quad * 8;
        const float* phh = W_hh + (size_t)r * HID + quad * 8;
#pragma unroll
        for (int kk = 0; kk < 8; ++kk) {
            Aih[q][kk] = cvt8(pih + kk * 32);
            Ahh[q][kk] = cvt8(phh + kk * 32);
        }
    }
    f32x4 biasv[4];
#pragma unroll
    for (int q = 0; q < 4; ++q)
#pragma unroll
        for (int r = 0; r < 4; ++r)
            biasv[q][r] = b_ih[q * HID + ulane + r] + b_hh[q * HID + ulane + r];

    float cst[4] = {0.f, 0.f, 0.f, 0.f};

    // ---- x B-fragments for t=0
    bf16x8 Bx[8];
    {
        int cap = caption[brow];
        const float* px = emb + (size_t)cap * HID + quad * 8;
#pragma unroll
        for (int kk = 0; kk < 8; ++kk) Bx[kk] = cvt8(px + kk * 32);
    }

    // poll assignment (threads 0..2, one peer flag each)
    const int myPeer = (ch + 1 + (int)threadIdx.x) & 3;
    // peer chunk ids for the cooperative load
    const int p0 = (ch + 1) & 3, p1 = (ch + 2) & 3, p2 = (ch + 3) & 3;
    // cooperative-load coordinates: thread covers (row cr, slot ck) for each
    // of the 3 peer chunks. 16 threads x 16 slots = 128B contiguous runs.
    const int cr = (int)threadIdx.x >> 4;   // h row 0..15
    const int ck = (int)threadIdx.x & 15;   // u64 slot within a 16-slot chunk

    for (int t = 0; t < TS; ++t) {
        // ---- 1. wait for peers' h(t-1) flags
        if (t > 0) {
            const unsigned tgt = (unsigned)t;
            if (threadIdx.x < 3) {
                while (__hip_atomic_load(flags + myPeer, __ATOMIC_RELAXED,
                                         __HIP_MEMORY_SCOPE_AGENT) < tgt) {}
            }
            asm volatile("" ::: "memory");   // spin may not move up
            __syncthreads();
        }

        // ---- 2. ISSUE peer co-load (3 u64/thread, peers only); results
        //          consumed at the stage step, so the RTT hides under x-MFMA
        unsigned long long pv0 = 0, pv1 = 0, pv2 = 0;
        if (t > 0) {
            const unsigned long long* hb = h_buf64
                + (size_t)((t - 1) & 1) * (BATCH * HID / 4)
                + (size_t)(b0 + cr) * (HID / 4) + ck;
            pv0 = __hip_atomic_load(hb + p0 * 16, __ATOMIC_RELAXED, __HIP_MEMORY_SCOPE_AGENT);
            pv1 = __hip_atomic_load(hb + p1 * 16, __ATOMIC_RELAXED, __HIP_MEMORY_SCOPE_AGENT);
            pv2 = __hip_atomic_load(hb + p2 * 16, __ATOMIC_RELAXED, __HIP_MEMORY_SCOPE_AGENT);
        }

        // ---- 3. ISSUE raw f32 gather of x(t+1); cvt deferred (no waitcnt here)
        f32x4 xr[16];
        {
            int tn = (t + 1 < TS) ? t + 1 : t;
            int cap = caption[tn * BATCH + brow];
            const float* px = emb + (size_t)cap * HID + quad * 8;
#pragma unroll
            for (int kk = 0; kk < 8; ++kk) {
                xr[2 * kk]     = *reinterpret_cast<const f32x4*>(px + kk * 32);
                xr[2 * kk + 1] = *reinterpret_cast<const f32x4*>(px + kk * 32 + 4);
            }
        }

        // ---- 4. x_t MFMAs (cover the in-flight loads above)
        f32x4 C[4];
#pragma unroll
        for (int q = 0; q < 4; ++q) C[q] = biasv[q];
#pragma unroll
        for (int kk = 0; kk < 8; ++kk) {
#pragma unroll
            for (int q = 0; q < 4; ++q)
                C[q] = __builtin_amdgcn_mfma_f32_16x16x32_bf16(Aih[q][kk], Bx[kk], C[q], 0, 0, 0);
        }

        if (t > 0) {
            // ---- 5. stage the 3 peer chunks into tile[(t-1)&1]
            char* tb = (char*)hlds[(t - 1) & 1];
            *(unsigned long long*)(tb + cr * 512 + ((p0 * 128 + ck * 8) ^ (cr << 4))) = pv0;
            *(unsigned long long*)(tb + cr * 512 + ((p1 * 128 + ck * 8) ^ (cr << 4))) = pv1;
            *(unsigned long long*)(tb + cr * 512 + ((p2 * 128 + ck * 8) ^ (cr << 4))) = pv2;
            __syncthreads();   // stage complete (own chunk written last step)

            // ---- 6. Hall ds_reads; cvt of xr scheduled under their latency
            const char* rb = (const char*)hlds[(t - 1) & 1];
            bf16x8 Hall[8];
#pragma unroll
            for (int kk = 0; kk < 8; ++kk) {
                const int phys = j * 512 + ((kk * 64 + quad * 16) ^ (j << 4));
                Hall[kk] = *reinterpret_cast<const bf16x8*>(rb + phys);
            }
#pragma unroll
            for (int kk = 0; kk < 8; ++kk) Bx[kk] = cvt8r(xr[2 * kk], xr[2 * kk + 1]);

#pragma unroll
            for (int kk = 0; kk < 8; ++kk) {
#pragma unroll
                for (int q = 0; q < 4; ++q)
                    C[q] = __builtin_amdgcn_mfma_f32_16x16x32_bf16(Ahh[q][kk], Hall[kk], C[q], 0, 0, 0);
            }
        } else {
            // t==0: just convert the gathered x(1)
#pragma unroll
            for (int kk = 0; kk < 8; ++kk) Bx[kk] = cvt8r(xr[2 * kk], xr[2 * kk + 1]);
        }

        // ---- 7. LSTM cell
        float hval[4];
        unsigned long long hpack = 0;
#pragma unroll
        for (int r = 0; r < 4; ++r) {
            float ig = sigm(C[0][r]);
            float fg = sigm(C[1][r]);
            float gg = tanh_f(C[2][r]);
            float og = sigm(C[3][r]);
            float c = fg * cst[r] + ig * gg;
            cst[r] = c;
            float h = og * tanh_f(c);
            hval[r] = h;
            hpack |= ((unsigned long long)f2bf(h)) << (16 * r);
        }

        // ---- 8. publish h(t) for peers (global) and for ourselves (LDS)
        {
            unsigned long long* hw = h_buf64 + (size_t)(t & 1) * (BATCH * HID / 4);
            __hip_atomic_store(hw + (((size_t)brow * HID + ulane) >> 2), hpack,
                               __ATOMIC_RELAXED, __HIP_MEMORY_SCOPE_AGENT);
            char* tb = (char*)hlds[t & 1];
            *(unsigned long long*)(tb + j * 512 + ((ulane * 2) ^ (j << 4))) = hpack;
        }

        __syncthreads();   // vmcnt drained -> h stores performed at MALL
        asm volatile("" ::: "memory");   // flag store may not sink below here
        if (threadIdx.x == 0)
            __hip_atomic_store(flags + ch, (unsigned)(t + 1),
                               __ATOMIC_RELAXED, __HIP_MEMORY_SCOPE_AGENT);
        asm volatile("" ::: "memory");   // ...nor past the next spin

        // ---- 9. out store: coalesced f32x4, off the critical path
        {
            f32x4 o;
#pragma unroll
            for (int r = 0; r < 4; ++r) o[r] = hval[r] + imgv[r];
            *reinterpret_cast<f32x4*>(out + ((size_t)t * BATCH + brow) * HID + ulane) = o;
        }
    }
}

// ---------------------------------------------------------------------------
extern "C" void kernel_launch(void* const* d_in, const int* in_sizes, int n_in,
                              void* d_out, int out_size, void* d_ws, size_t ws_size,
                              hipStream_t stream) {
    const float* img_feature = (const float*)d_in[0];   // [1024, 2048] fp32
    const int*   caption     = (const int*)d_in[1];     // [64, 1024] int32
    const float* W_img       = (const float*)d_in[2];   // [256, 2048] fp32
    const float* b_img       = (const float*)d_in[3];   // [256] fp32
    const float* emb         = (const float*)d_in[4];   // [32000, 256] fp32
    const float* W_ih        = (const float*)d_in[5];   // [1024, 256] fp32
    const float* W_hh        = (const float*)d_in[6];   // [1024, 256] fp32
    const float* b_ih        = (const float*)d_in[7];   // [1024] fp32
    const float* b_hh        = (const float*)d_in[8];   // [1024] fp32
    float* out = (float*)d_out;                         // [64,1024,256] fp32

    uint8_t* ws = (uint8_t*)d_ws;
    unsigned* ctr = (unsigned*)ws;                                  // 64 groups * 64B = 4KB
    unsigned long long* h_buf64 = (unsigned long long*)(ws + 4096); // 2 x 512KB bf16 h

    // ws is poisoned 0xAA before every timed launch: zero the sync flags
    hipMemsetAsync(ctr, 0, 4096, stream);

    lstm_kernel<<<256, 256, 0, stream>>>(img_feature, caption, W_img, b_img, emb,
                                         W_ih, W_hh, b_ih, b_hh, h_buf64, ctr, out);
}